// Round 1
// baseline (63.507 us; speedup 1.0000x reference)
//
#include <hip/hip_runtime.h>

// Problem constants (from reference setup_inputs): B=128, N=1024, D=8, S=64
constexpr int B  = 128;
constexpr int N  = 1024;
constexpr int DS = 512;   // D*S, contiguous innermost per (b,n)

// Kernel 1: one wave (64 lanes) per (b,n) pair.
// wave id w: n = w>>7, b = w&127  -> block (4 waves) covers 4 consecutive b of the SAME n,
// so the block can share one LDS spike counter and emit a single atomicAdd per block.
__global__ __launch_bounds__(256) void mpjrd_spike_kernel(
    const float* __restrict__ x,      // [B,N,DS]
    const float* __restrict__ W,      // [N,DS]
    const float* __restrict__ theta,  // [N]
    float*       __restrict__ spikes, // [B,N] (d_out[0 .. B*N))
    int*         __restrict__ counts) // [N] spike counts (workspace, pre-zeroed)
{
    __shared__ int cnt;
    const int tid  = threadIdx.x;
    const int lane = tid & 63;
    const int w    = blockIdx.x * 4 + (tid >> 6);  // global wave id
    const int n    = w >> 7;    // w / 128
    const int b    = w & 127;   // w % 128

    if (tid == 0) cnt = 0;
    __syncthreads();

    const size_t xbase = ((size_t)b * N + n) * DS;
    const size_t wbase = (size_t)n * DS;

    // Each lane: two float4 of x and of W. Lanes 0..63 * 4 floats cover 0..255,
    // second load covers 256..511. Fully coalesced 1 KiB per wave per instruction.
    const float4 xa = *reinterpret_cast<const float4*>(x + xbase + (size_t)lane * 4);
    const float4 xb = *reinterpret_cast<const float4*>(x + xbase + 256 + (size_t)lane * 4);
    const float4 wa = *reinterpret_cast<const float4*>(W + wbase + (size_t)lane * 4);
    const float4 wb = *reinterpret_cast<const float4*>(W + wbase + 256 + (size_t)lane * 4);

    // fp64 accumulation: fp32*fp32 is exact in fp64; keeps the hard-threshold
    // decision v >= theta bit-stable vs a high-precision reference.
    double acc = (double)xa.x * (double)wa.x;
    acc += (double)xa.y * (double)wa.y;
    acc += (double)xa.z * (double)wa.z;
    acc += (double)xa.w * (double)wa.w;
    acc += (double)xb.x * (double)wb.x;
    acc += (double)xb.y * (double)wb.y;
    acc += (double)xb.z * (double)wb.z;
    acc += (double)xb.w * (double)wb.w;

    // Wave-wide tree reduction (64 lanes).
    #pragma unroll
    for (int off = 32; off > 0; off >>= 1)
        acc += __shfl_down(acc, off);

    if (lane == 0) {
        const float spike = (acc >= (double)theta[n]) ? 1.0f : 0.0f;
        spikes[(size_t)b * N + n] = spike;
        if (spike != 0.0f) atomicAdd(&cnt, 1);
    }
    __syncthreads();
    if (tid == 0 && cnt != 0) atomicAdd(&counts[n], cnt);
}

// Kernel 2: per-n epilogue -> rates, thetas, r_hats appended after spikes.
__global__ __launch_bounds__(256) void mpjrd_finalize_kernel(
    const int*   __restrict__ counts,
    const float* __restrict__ theta,
    const float* __restrict__ r_hat,
    float*       __restrict__ out)   // d_out base
{
    const int n = blockIdx.x * blockDim.x + threadIdx.x;
    if (n >= N) return;
    const float rate = (float)counts[n] * (1.0f / 128.0f);
    const float rh   = 0.95f * r_hat[n] + 0.05f * rate;   // (1-ALPHA)*r_hat + ALPHA*rate
    const float th   = theta[n] + 0.1f * (rh - 0.1f);     // theta + THETA_LR*(rh - R_TARGET)
    out[(size_t)B * N + n]         = rate;   // rates
    out[(size_t)B * N + N + n]     = th;     // thetas
    out[(size_t)B * N + 2 * N + n] = rh;     // r_hats
}

extern "C" void kernel_launch(void* const* d_in, const int* in_sizes, int n_in,
                              void* d_out, int out_size, void* d_ws, size_t ws_size,
                              hipStream_t stream) {
    const float* x     = (const float*)d_in[0];
    const float* W     = (const float*)d_in[1];
    const float* theta = (const float*)d_in[2];
    const float* r_hat = (const float*)d_in[3];
    float* out = (float*)d_out;
    int* counts = (int*)d_ws;

    // Zero per-n spike counters (graph-capture-safe async memset).
    hipMemsetAsync(counts, 0, N * sizeof(int), stream);

    // B*N = 131072 waves, 4 waves per 256-thread block -> 32768 blocks.
    mpjrd_spike_kernel<<<(B * N) / 4, 256, 0, stream>>>(x, W, theta, out, counts);
    mpjrd_finalize_kernel<<<N / 256, 256, 0, stream>>>(counts, theta, r_hat, out);
}

// Round 2
// 49.378 us; speedup vs baseline: 1.2861x; 1.2861x over previous
//
#include <hip/hip_runtime.h>

// Problem constants (from reference setup_inputs): B=128, N=1024, D=8, S=64
constexpr int B  = 128;
constexpr int N  = 1024;
constexpr int DS = 512;             // D*S, contiguous innermost per (b,n)
constexpr int WPN = 8;              // waves per neuron
constexpr int BPW = B / WPN;        // b's per wave = 16

typedef float f32x4 __attribute__((ext_vector_type(4)));

// Kernel 1: persistent waves. Wave w owns n = w/8 and b in [g*16, g*16+16), g = w%8.
// W[n] and theta[n] live in registers for all 16 iterations. Lane 0 accumulates
// its own spike count -> one partial write per wave, no atomics, no memset.
__global__ __launch_bounds__(256) void mpjrd_spike_kernel(
    const float* __restrict__ x,       // [B,N,DS]
    const float* __restrict__ W,       // [N,DS]
    const float* __restrict__ theta,   // [N]
    float*       __restrict__ out,     // d_out: spikes [B,N] at offset 0
    float*       __restrict__ partial) // ws: [N,WPN] per-wave spike counts
{
    const int tid  = threadIdx.x;
    const int lane = tid & 63;
    const int w    = blockIdx.x * 4 + (tid >> 6);   // global wave id, 0..8191
    const int n    = w >> 3;
    const int g    = w & 7;

    // Hoist W[n] (512 floats -> 8 per lane) and theta[n] into registers.
    const size_t wbase = (size_t)n * DS + (size_t)lane * 4;
    const f32x4 w0 = *reinterpret_cast<const f32x4*>(W + wbase);
    const f32x4 w1 = *reinterpret_cast<const f32x4*>(W + wbase + 256);
    const double th = (double)theta[n];

    float cnt = 0.0f;
    const int b0 = g * BPW;

    #pragma unroll 4
    for (int i = 0; i < BPW; ++i) {
        const int b = b0 + i;
        const float* xp = x + ((size_t)b * N + n) * DS + (size_t)lane * 4;
        // Streamed exactly once: nontemporal to keep x out of L2's way.
        const f32x4 x0 = __builtin_nontemporal_load(reinterpret_cast<const f32x4*>(xp));
        const f32x4 x1 = __builtin_nontemporal_load(reinterpret_cast<const f32x4*>(xp + 256));

        // fp64 accumulation: fp32*fp32 exact in fp64 -> threshold decision
        // matches the high-precision numpy reference.
        double acc = (double)x0.x * (double)w0.x;
        acc += (double)x0.y * (double)w0.y;
        acc += (double)x0.z * (double)w0.z;
        acc += (double)x0.w * (double)w0.w;
        acc += (double)x1.x * (double)w1.x;
        acc += (double)x1.y * (double)w1.y;
        acc += (double)x1.z * (double)w1.z;
        acc += (double)x1.w * (double)w1.w;

        #pragma unroll
        for (int off = 32; off > 0; off >>= 1)
            acc += __shfl_down(acc, off);

        if (lane == 0) {
            const float s = (acc >= th) ? 1.0f : 0.0f;
            out[(size_t)b * N + n] = s;
            cnt += s;
        }
    }
    if (lane == 0) partial[n * WPN + g] = cnt;
}

// Kernel 2: one thread per neuron. Sum 8 partials, emit rates/thetas/r_hats.
__global__ __launch_bounds__(256) void mpjrd_finalize_kernel(
    const float* __restrict__ partial,
    const float* __restrict__ theta,
    const float* __restrict__ r_hat,
    float*       __restrict__ out)
{
    const int n = blockIdx.x * 256 + threadIdx.x;
    float c = 0.0f;
    #pragma unroll
    for (int i = 0; i < WPN; ++i) c += partial[n * WPN + i];
    const float rate = c * (1.0f / 128.0f);
    const float rh   = 0.95f * r_hat[n] + 0.05f * rate;  // (1-ALPHA)*r_hat + ALPHA*rate
    const float th   = theta[n] + 0.1f * (rh - 0.1f);    // theta + THETA_LR*(rh - R_TARGET)
    out[(size_t)B * N + n]         = rate;   // rates
    out[(size_t)B * N + N + n]     = th;     // thetas
    out[(size_t)B * N + 2 * N + n] = rh;     // r_hats
}

extern "C" void kernel_launch(void* const* d_in, const int* in_sizes, int n_in,
                              void* d_out, int out_size, void* d_ws, size_t ws_size,
                              hipStream_t stream) {
    const float* x     = (const float*)d_in[0];
    const float* W     = (const float*)d_in[1];
    const float* theta = (const float*)d_in[2];
    const float* r_hat = (const float*)d_in[3];
    float* out     = (float*)d_out;
    float* partial = (float*)d_ws;   // N*WPN floats = 32 KB, written before read

    // 8192 waves = 2048 blocks x 256 threads (4 waves/block).
    mpjrd_spike_kernel<<<(N * WPN) / 4, 256, 0, stream>>>(x, W, theta, out, partial);
    mpjrd_finalize_kernel<<<N / 256, 256, 0, stream>>>(partial, theta, r_hat, out);
}

// Round 3
// 47.538 us; speedup vs baseline: 1.3359x; 1.0387x over previous
//
#include <hip/hip_runtime.h>

// Problem constants: B=128, N=1024, D=8, S=64
constexpr int B   = 128;
constexpr int N   = 1024;
constexpr int DS  = 512;            // D*S, contiguous innermost per (b,n)
constexpr int NC  = 8;              // n-chunk per wave/block
constexpr int NCH = N / NC;         // 128 chunks
constexpr int BQ  = 4;              // b's per block (one per wave)
constexpr int NBQ = B / BQ;         // 32 b-quads

typedef float f32x4 __attribute__((ext_vector_type(4)));

// Kernel 1: block = 4 waves = (b-quad, n-chunk). W tile (8 n, 16 KB) staged in
// LDS once per block. Each wave streams 16 KB of x CONTIGUOUSLY (8 consecutive
// n of one b) -> long DRAM runs instead of 2KB-granule hopping.
__global__ __launch_bounds__(256) void mpjrd_spike_kernel(
    const float* __restrict__ x,       // [B,N,DS]
    const float* __restrict__ W,       // [N,DS]
    const float* __restrict__ theta,   // [N]
    float*       __restrict__ out,     // d_out: spikes [B,N]
    float*       __restrict__ partial) // ws: [NBQ][N] per-quad spike counts
{
    __shared__ float Wl[NC * DS];      // 16 KB W tile
    __shared__ float thl[NC];
    __shared__ float s_cnt[BQ][NC];

    const int tid  = threadIdx.x;
    const int lane = tid & 63;
    const int g    = tid >> 6;                 // wave in block = b within quad
    const int nc   = blockIdx.x & (NCH - 1);   // n-chunk (consecutive blocks -> consecutive x)
    const int bq   = blockIdx.x >> 7;          // b-quad
    const int n0   = nc * NC;
    const int b    = bq * BQ + g;

    // Stage W tile: 4096 floats = 1024 float4, 4 per thread, coalesced.
    {
        const f32x4* Wg = reinterpret_cast<const f32x4*>(W + (size_t)n0 * DS);
        f32x4* Wd = reinterpret_cast<f32x4*>(Wl);
        #pragma unroll
        for (int r = 0; r < 4; ++r) Wd[tid + r * 256] = Wg[tid + r * 256];
        if (tid < NC) thl[tid] = theta[n0 + tid];
    }
    __syncthreads();

    const float* xp0 = x + ((size_t)b * N + n0) * DS + (size_t)lane * 4;
    float spk[NC];

    #pragma unroll
    for (int j = 0; j < NC; ++j) {
        const float* xp = xp0 + (size_t)j * DS;
        const f32x4 x0 = __builtin_nontemporal_load(reinterpret_cast<const f32x4*>(xp));
        const f32x4 x1 = __builtin_nontemporal_load(reinterpret_cast<const f32x4*>(xp + 256));
        const f32x4 wa = *reinterpret_cast<const f32x4*>(Wl + j * DS + lane * 4);
        const f32x4 wb = *reinterpret_cast<const f32x4*>(Wl + j * DS + lane * 4 + 256);

        // fp64 accumulation: fp32*fp32 exact in fp64 -> threshold decisions
        // bit-stable vs the high-precision numpy reference (absmax 0.0 so far).
        double acc = (double)x0.x * (double)wa.x;
        acc += (double)x0.y * (double)wa.y;
        acc += (double)x0.z * (double)wa.z;
        acc += (double)x0.w * (double)wa.w;
        acc += (double)x1.x * (double)wb.x;
        acc += (double)x1.y * (double)wb.y;
        acc += (double)x1.z * (double)wb.z;
        acc += (double)x1.w * (double)wb.w;

        #pragma unroll
        for (int off = 32; off > 0; off >>= 1)
            acc += __shfl_down(acc, off);

        spk[j] = (acc >= (double)thl[j]) ? 1.0f : 0.0f;
    }

    if (lane == 0) {
        // Spikes for 8 consecutive n of this b: two contiguous float4 stores.
        f32x4* op = reinterpret_cast<f32x4*>(out + (size_t)b * N + n0);
        op[0] = f32x4{spk[0], spk[1], spk[2], spk[3]};
        op[1] = f32x4{spk[4], spk[5], spk[6], spk[7]};
        #pragma unroll
        for (int j = 0; j < NC; ++j) s_cnt[g][j] = spk[j];
    }
    __syncthreads();
    if (tid < NC) {
        partial[(size_t)bq * N + n0 + tid] =
            s_cnt[0][tid] + s_cnt[1][tid] + s_cnt[2][tid] + s_cnt[3][tid];
    }
}

// Kernel 2: thread per neuron; sum 32 quad-partials (coalesced), emit epilogue.
__global__ __launch_bounds__(256) void mpjrd_finalize_kernel(
    const float* __restrict__ partial,
    const float* __restrict__ theta,
    const float* __restrict__ r_hat,
    float*       __restrict__ out)
{
    const int n = blockIdx.x * 256 + threadIdx.x;
    float c = 0.0f;
    #pragma unroll
    for (int i = 0; i < NBQ; ++i) c += partial[(size_t)i * N + n];
    const float rate = c * (1.0f / 128.0f);
    const float rh   = 0.95f * r_hat[n] + 0.05f * rate;  // (1-ALPHA)*r_hat + ALPHA*rate
    const float th   = theta[n] + 0.1f * (rh - 0.1f);    // theta + THETA_LR*(rh - R_TARGET)
    out[(size_t)B * N + n]         = rate;   // rates
    out[(size_t)B * N + N + n]     = th;     // thetas
    out[(size_t)B * N + 2 * N + n] = rh;     // r_hats
}

extern "C" void kernel_launch(void* const* d_in, const int* in_sizes, int n_in,
                              void* d_out, int out_size, void* d_ws, size_t ws_size,
                              hipStream_t stream) {
    const float* x     = (const float*)d_in[0];
    const float* W     = (const float*)d_in[1];
    const float* theta = (const float*)d_in[2];
    const float* r_hat = (const float*)d_in[3];
    float* out     = (float*)d_out;
    float* partial = (float*)d_ws;   // NBQ*N floats = 128 KB, fully written each call

    mpjrd_spike_kernel<<<NBQ * NCH, 256, 0, stream>>>(x, W, theta, out, partial);
    mpjrd_finalize_kernel<<<N / 256, 256, 0, stream>>>(partial, theta, r_hat, out);
}